// Round 6
// baseline (22390.686 us; speedup 1.0000x reference)
//
#include <hip/hip_runtime.h>
#include <cmath>

// ============================================================================
// Fused 2-layer GRU (B=128, T=512, d=512) + projection, fp32.
// ONE persistent cooperative kernel, 256 WGs x 512 thr (8 waves = 2/SIMD).
// Pipeline skew: iter g computes L0 step g AND L1 step g-1.
// r6 changes (r5 counters: VALUBusy 19%, Occupancy 12%, latency-bound):
//   - 512 threads/WG: wave-halves split batch rows 0-15/16-31. Same K-split,
//     same scratch layout, same LDS bytes; per-thread FMA halves; 2 waves/SIMD
//     hide each other's L3/barrier stalls.
//   - pass-C chunk-0 h1 loads + gate-phase h_prev loads issued at iter top.
//   - h exchange via relaxed agent-scope atomics (sc0sc1 coherent, unordered)
//     instead of volatile -> compiler free to batch/pipeline them.
// ============================================================================

#define TSEQ   512
#define NB     128
#define DM     512
#define ENCF   21
#define PREDL  96
#define TSTART 416
#define NTHR   512
#define NBLK   256

// LDS layout (float indices) — unchanged from r5 (155,936 B)
#define L_WHH0 0                    // [24][512] swizzled
#define L_WHH1 (24*DM)              // [24][512] swizzled
#define L_HCH  (2*24*DM)            // [32][128] swizzled h chunk
#define L_SC0  (L_HCH + 32*128)     // [4][32][33] reduce scratch L0
#define L_SC1  (L_SC0 + 4*32*33)    // [4][32][33] reduce scratch L1
#define L_BIA0 (L_SC1 + 4*32*33)    // 48
#define L_BIA1 (L_BIA0 + 48)        // 48
#define L_WIH0 (L_BIA1 + 48)        // [24][24]
#define L_XCH  (L_WIH0 + 24*24)     // [32][24]
#define L_WP   (L_XCH + 32*24)      // [21][8]
#define L_HNT  (L_WP + 168)         // [32][8]
#define LDS_FLOATS (L_HNT + 256)
#define LDS_BYTES  (LDS_FLOATS * 4)

// uniform bank-quad swizzle: bits {2,4} from row bits {0,1}
#define SWZB(x) (((((x) & 1) << 2)) | ((((x) & 2)) << 3))

__device__ float g_h0A[NB * DM];
__device__ float g_h0B[NB * DM];
__device__ float g_h1A[NB * DM];
__device__ float g_h1B[NB * DM];
__device__ unsigned g_bar[16];

extern "C" __global__ void zero_bar_kernel() {
  if (threadIdx.x < 16)
    __hip_atomic_store(&g_bar[threadIdx.x], 0u, __ATOMIC_RELAXED, __HIP_MEMORY_SCOPE_AGENT);
}

__device__ __forceinline__ float sigf(float x) { return 1.0f / (1.0f + expf(-x)); }

// device-coherent relaxed atomic accesses (sc0 sc1, unordered -> pipelineable)
__device__ __forceinline__ float2 ld2_dc(const float* p) {
  unsigned long long v = __hip_atomic_load((unsigned long long*)p,
                                           __ATOMIC_RELAXED, __HIP_MEMORY_SCOPE_AGENT);
  union { unsigned long long u; float2 f; } cv; cv.u = v; return cv.f;
}
__device__ __forceinline__ float ld_dc(const float* p) {
  unsigned v = __hip_atomic_load((unsigned*)p,
                                 __ATOMIC_RELAXED, __HIP_MEMORY_SCOPE_AGENT);
  union { unsigned u; float f; } cv; cv.u = v; return cv.f;
}
__device__ __forceinline__ void st_dc(float* p, float v) {
  union { float f; unsigned u; } cv; cv.f = v;
  __hip_atomic_store((unsigned*)p, cv.u, __ATOMIC_RELAXED, __HIP_MEMORY_SCOPE_AGENT);
}

extern "C" __global__ __launch_bounds__(NTHR)
void gru2_fused(const float* __restrict__ x_enc,
                const float* __restrict__ Wih0, const float* __restrict__ Whh0,
                const float* __restrict__ bih0, const float* __restrict__ bhh0,
                const float* __restrict__ Wih1, const float* __restrict__ Whh1,
                const float* __restrict__ bih1, const float* __restrict__ bhh1,
                const float* __restrict__ Wproj, const float* __restrict__ bproj,
                float* __restrict__ outp)
{
  extern __shared__ float lds[];

  const int tid  = threadIdx.x;
  const int bid  = blockIdx.x;
  const int bt   = bid & 3;         // batch group (32 rows), barrier group
  const int jt   = bid >> 2;        // j tile 0..63 (8 hidden units)
  const int b0   = bt << 5;
  const int j0   = jt << 3;
  const int l    = tid & 63;
  const int wv   = tid >> 6;        // wave 0..7
  const int wq   = wv & 3;          // k-wave within half (scratch slot)
  const int half = wv >> 2;         // batch half: rows 0-15 / 16-31
  const int pr   = l & 3;           // row position
  const int pb4  = (l >> 2) & 3;    // batch position mod 4
  const int kg   = l >> 4;          // lane k-group 0..3

  const float2 z2 = make_float2(0.f, 0.f);

  // ---- one-time staging: W_hh0/W_hh1 (swizzled), W_ih0, biases, W_proj ----
  for (int f = tid; f < 24 * 128; f += NTHR) {
    int r = f >> 7, w4 = f & 127;
    int R = ((r >> 3) << 9) + j0 + (r & 7);
    int dst = r * DM + ((w4 << 2) ^ SWZB(r));
    *(float4*)(lds + L_WHH0 + dst) = *(const float4*)(Whh0 + (size_t)R * DM + (w4 << 2));
    *(float4*)(lds + L_WHH1 + dst) = *(const float4*)(Whh1 + (size_t)R * DM + (w4 << 2));
  }
  for (int idx = tid; idx < 24 * ENCF; idx += NTHR) {
    int r = idx / ENCF, kx = idx - r * ENCF;
    int R = ((r >> 3) << 9) + j0 + (r & 7);
    lds[L_WIH0 + r * 24 + kx] = Wih0[R * ENCF + kx];
  }
  if (tid < 24) {
    int R = ((tid >> 3) << 9) + j0 + (tid & 7);
    lds[L_BIA0 + tid]      = bhh0[R];
    lds[L_BIA0 + 24 + tid] = bih0[R];
    lds[L_BIA1 + tid]      = bhh1[R];
    lds[L_BIA1 + 24 + tid] = bih1[R];
  }
  for (int idx = tid; idx < 21 * 8; idx += NTHR) {
    int o = idx >> 3, j = idx & 7;
    lds[L_WP + idx] = Wproj[o * DM + j0 + j];
  }
  // visibility covered by first __syncthreads in the chunk loop

#pragma unroll 1
  for (int g = 0; g <= TSEQ; ++g) {
    const float* h0r = (g & 1) ? g_h0A : g_h0B;   // h0_{g-1}
    float*       h0w = (g & 1) ? g_h0B : g_h0A;   // h0_g
    const float* h1r = (g & 1) ? g_h1B : g_h1A;   // h1_{g-2}
    float*       h1w = (g & 1) ? g_h1A : g_h1B;   // h1_{g-1}

    // ---- iteration-top prefetches (hide L3 latency under pass A) ----
    // x slice (regs)
    const int gx = (g < TSEQ) ? g : (TSEQ - 1);
    float rx[2];
#pragma unroll
    for (int q = 0; q < 2; ++q) {
      int idx = tid + (q << 9);
      float v = 0.0f;
      if (idx < 32 * ENCF) {
        int row = idx / ENCF, kx = idx - row * ENCF;
        v = x_enc[((size_t)(b0 + row) * TSEQ + gx) * ENCF + kx];
      }
      rx[q] = v;
    }
    // gate-phase h_prev scalars
    float h0prev = 0.f, h1prev = 0.f;
    size_t hix = 0;
    if (tid < 256) {
      int b = tid >> 3, j = tid & 7;
      hix = (size_t)(b0 + b) * DM + j0 + j;
      if (g > 0) h0prev = ld_dc(h0r + hix);
      if (g > 1) h1prev = ld_dc(h1r + hix);
    }
    // chunk-0 of BOTH passes (8 coherent 8B loads in flight)
    float2 ph0[4], ph1[4];
#pragma unroll
    for (int q = 0; q < 4; ++q) {
      int idx = tid + (q << 9);            // 0..2047 doubles
      int row = idx >> 6, c2 = idx & 63;
      size_t off = (size_t)(b0 + row) * DM + (c2 << 1);
      ph0[q] = (g == 0) ? z2 : ld2_dc(h0r + off);
      ph1[q] = (g <= 1) ? z2 : ld2_dc(h1r + off);
    }

    float accA[4][6], accX[4][6];
#pragma unroll
    for (int i = 0; i < 4; ++i)
#pragma unroll
      for (int m = 0; m < 6; ++m) { accA[i][m] = 0.0f; accX[i][m] = 0.0f; }

    // ---- pass A+B: h0_{g-1} x (W_hh0 from LDS, W_ih1 from global/L2) ----
#pragma unroll 1
    for (int c = 0; c < 4; ++c) {
      __syncthreads();                             // prev chunk compute done
#pragma unroll
      for (int q = 0; q < 4; ++q) {
        int idx = tid + (q << 9);
        int row = idx >> 6, cf = (idx & 63) << 1;
        *(float2*)(lds + L_HCH + row * 128 + (cf ^ SWZB(row))) = ph0[q];
      }
      __syncthreads();
      if (c < 3) {
#pragma unroll
        for (int q = 0; q < 4; ++q) {
          int idx = tid + (q << 9);
          int row = idx >> 6, c2 = idx & 63;
          ph0[q] = (g == 0) ? z2
                 : ld2_dc(h0r + (size_t)(b0 + row) * DM + ((c + 1) << 7) + (c2 << 1));
        }
      }
      float4 wx[6][2];
#pragma unroll
      for (int m = 0; m < 6; ++m) {
        int r = pr + (m << 2);
        int R = ((r >> 3) << 9) + j0 + (r & 7);
#pragma unroll
        for (int q = 0; q < 2; ++q) {
          int ww = (wq << 3) + (kg << 1) + q;
          wx[m][q] = *(const float4*)(Wih1 + (size_t)R * DM + (((c << 5) + ww) << 2));
        }
      }
#pragma unroll
      for (int q = 0; q < 2; ++q) {
        int ww = (wq << 3) + (kg << 1) + q;
        int colf = ((c << 5) + ww) << 2;
        float4 wh[6];
#pragma unroll
        for (int m = 0; m < 6; ++m) {
          int r = pr + (m << 2);
          wh[m] = *(const float4*)(lds + L_WHH0 + r * DM + (colf ^ SWZB(r)));
        }
#pragma unroll
        for (int i = 0; i < 4; ++i) {
          int b = pb4 + (i << 2) + (half << 4);
          float4 hv = *(const float4*)(lds + L_HCH + b * 128 + ((ww << 2) ^ SWZB(b)));
#pragma unroll
          for (int m = 0; m < 6; ++m) {
            accA[i][m] += hv.x * wh[m].x + hv.y * wh[m].y + hv.z * wh[m].z + hv.w * wh[m].w;
            accX[i][m] += hv.x * wx[m][q].x + hv.y * wx[m][q].y + hv.z * wx[m][q].z + hv.w * wx[m][q].w;
          }
        }
      }
    }

    // reduce A -> sc0 (=), X -> sc1 (=); lane kg-groups via shfl
#pragma unroll
    for (int i = 0; i < 4; ++i)
#pragma unroll
      for (int m = 0; m < 6; ++m) {
        float a = accA[i][m]; a += __shfl_xor(a, 16); a += __shfl_xor(a, 32); accA[i][m] = a;
        float x = accX[i][m]; x += __shfl_xor(x, 16); x += __shfl_xor(x, 32); accX[i][m] = x;
      }
    if (kg == 0) {
#pragma unroll
      for (int i = 0; i < 4; ++i) {
        int b = pb4 + (i << 2) + (half << 4);
        float* s0 = lds + L_SC0 + (wq * 32 + b) * 33;
        float* s1 = lds + L_SC1 + (wq * 32 + b) * 33;
#pragma unroll
        for (int m = 0; m < 6; ++m) {
          int r = pr + (m << 2);
          s0[r] = accA[i][m];
          s1[(m < 4) ? r : (r + 8)] = accX[i][m];   // n-gate x-part at 24..31
        }
      }
    }

    // ---- pass C: h1_{g-2} x W_hh1 (LDS); chunk0 already in ph1 ----
#pragma unroll
    for (int i = 0; i < 4; ++i)
#pragma unroll
      for (int m = 0; m < 6; ++m) accA[i][m] = 0.0f;

#pragma unroll 1
    for (int c = 0; c < 4; ++c) {
      __syncthreads();
#pragma unroll
      for (int q = 0; q < 4; ++q) {
        int idx = tid + (q << 9);
        int row = idx >> 6, cf = (idx & 63) << 1;
        *(float2*)(lds + L_HCH + row * 128 + (cf ^ SWZB(row))) = ph1[q];
      }
      __syncthreads();
      if (c < 3) {
#pragma unroll
        for (int q = 0; q < 4; ++q) {
          int idx = tid + (q << 9);
          int row = idx >> 6, c2 = idx & 63;
          ph1[q] = (g <= 1) ? z2
                 : ld2_dc(h1r + (size_t)(b0 + row) * DM + ((c + 1) << 7) + (c2 << 1));
        }
      }
#pragma unroll
      for (int q = 0; q < 2; ++q) {
        int ww = (wq << 3) + (kg << 1) + q;
        int colf = ((c << 5) + ww) << 2;
        float4 wh[6];
#pragma unroll
        for (int m = 0; m < 6; ++m) {
          int r = pr + (m << 2);
          wh[m] = *(const float4*)(lds + L_WHH1 + r * DM + (colf ^ SWZB(r)));
        }
#pragma unroll
        for (int i = 0; i < 4; ++i) {
          int b = pb4 + (i << 2) + (half << 4);
          float4 hv = *(const float4*)(lds + L_HCH + b * 128 + ((ww << 2) ^ SWZB(b)));
#pragma unroll
          for (int m = 0; m < 6; ++m)
            accA[i][m] += hv.x * wh[m].x + hv.y * wh[m].y + hv.z * wh[m].z + hv.w * wh[m].w;
        }
      }
    }

    // reduce C -> sc1: rows 0..15 (+=, join x-part), 16..23 (=, n-gate h-part)
#pragma unroll
    for (int i = 0; i < 4; ++i)
#pragma unroll
      for (int m = 0; m < 6; ++m) {
        float a = accA[i][m]; a += __shfl_xor(a, 16); a += __shfl_xor(a, 32); accA[i][m] = a;
      }
    if (kg == 0) {
#pragma unroll
      for (int i = 0; i < 4; ++i) {
        int b = pb4 + (i << 2) + (half << 4);
        float* s1 = lds + L_SC1 + (wq * 32 + b) * 33;
#pragma unroll
        for (int m = 0; m < 6; ++m) {
          int r = pr + (m << 2);
          if (m < 4) s1[r] += accA[i][m];          // same thread wrote '=' above
          else       s1[r]  = accA[i][m];
        }
      }
    }

    // stage x slice for L0 gate threads
#pragma unroll
    for (int q = 0; q < 2; ++q) {
      int idx = tid + (q << 9);
      if (idx < 32 * ENCF) {
        int row = idx / ENCF, kx = idx - row * ENCF;
        lds[L_XCH + row * 24 + kx] = rx[q];
      }
    }
    __syncthreads();

    // ---- gates: threads 0..255 -> (b = tid>>3, j = tid&7) ----
    if (tid < 256) {
      int b = tid >> 3, j = tid & 7;
      float sR0 = 0.f, sZ0 = 0.f, sN0 = 0.f;
      float sR1 = 0.f, sZ1 = 0.f, sN1h = 0.f, sN1x = 0.f;
#pragma unroll
      for (int w = 0; w < 4; ++w) {
        const float* s0 = lds + L_SC0 + (w * 32 + b) * 33;
        const float* s1 = lds + L_SC1 + (w * 32 + b) * 33;
        sR0 += s0[j]; sZ0 += s0[8 + j]; sN0 += s0[16 + j];
        sR1 += s1[j]; sZ1 += s1[8 + j]; sN1h += s1[16 + j]; sN1x += s1[24 + j];
      }
      if (g < TSEQ) {
        float xr = 0.f, xz = 0.f, xn = 0.f;
        const float* xrow = lds + L_XCH + b * 24;
#pragma unroll
        for (int k = 0; k < ENCF; ++k) {
          float xv = xrow[k];
          xr += xv * lds[L_WIH0 + j * 24 + k];
          xz += xv * lds[L_WIH0 + (8 + j) * 24 + k];
          xn += xv * lds[L_WIH0 + (16 + j) * 24 + k];
        }
        float r0 = sigf(xr + lds[L_BIA0 + 24 + j] + sR0 + lds[L_BIA0 + j]);
        float z0 = sigf(xz + lds[L_BIA0 + 32 + j] + sZ0 + lds[L_BIA0 + 8 + j]);
        float n0 = tanhf(xn + lds[L_BIA0 + 40 + j] + r0 * (sN0 + lds[L_BIA0 + 16 + j]));
        st_dc(h0w + hix, (1.0f - z0) * n0 + z0 * h0prev);
      }
      if (g >= 1) {
        float r1 = sigf(sR1 + lds[L_BIA1 + 24 + j] + lds[L_BIA1 + j]);
        float z1 = sigf(sZ1 + lds[L_BIA1 + 32 + j] + lds[L_BIA1 + 8 + j]);
        float n1 = tanhf(sN1x + lds[L_BIA1 + 40 + j] + r1 * (sN1h + lds[L_BIA1 + 16 + j]));
        float h1n = (1.0f - z1) * n1 + z1 * h1prev;
        st_dc(h1w + hix, h1n);
        lds[L_HNT + (b << 3) + j] = h1n;
      }
    }

    // ---- fused projection: h1_{g-1}, steps 416..511 -> iters 417..512 ----
    if (g >= TSTART + 1) {
      __syncthreads();
      int tp = g - 1 - TSTART;
#pragma unroll
      for (int q = 0; q < 2; ++q) {
        int idx = tid + (q << 9);
        if (idx < 32 * ENCF) {
          int b = idx / ENCF, o = idx - b * ENCF;
          const float* hb = lds + L_HNT + (b << 3);
          const float* wo = lds + L_WP + (o << 3);
          float v = hb[0] * wo[0] + hb[1] * wo[1] + hb[2] * wo[2] + hb[3] * wo[3]
                  + hb[4] * wo[4] + hb[5] * wo[5] + hb[6] * wo[6] + hb[7] * wo[7];
          if (jt == 0) v += bproj[o];
          atomicAdd(outp + ((size_t)(b0 + b) * PREDL + tp) * ENCF + o, v);
        }
      }
    }

    // ---- inter-WG barrier (64 WGs per batch group), fence-free ----
    __syncthreads();                 // drains vmcnt -> all h stores coherent
    if (tid == 0) {
      asm volatile("s_waitcnt vmcnt(0) lgkmcnt(0)" ::: "memory");
      __hip_atomic_fetch_add(&g_bar[bt], 1u, __ATOMIC_RELAXED, __HIP_MEMORY_SCOPE_AGENT);
      unsigned tgt = 64u * (unsigned)(g + 1);
      while (__hip_atomic_load(&g_bar[bt], __ATOMIC_RELAXED, __HIP_MEMORY_SCOPE_AGENT) < tgt)
        __builtin_amdgcn_s_sleep(2);
    }
    __syncthreads();
    asm volatile("" ::: "memory");
  }
}

extern "C" void kernel_launch(void* const* d_in, const int* in_sizes, int n_in,
                              void* d_out, int out_size, void* d_ws, size_t ws_size,
                              hipStream_t stream)
{
  (void)in_sizes; (void)n_in; (void)d_ws; (void)ws_size;
  const float* x_enc  = (const float*)d_in[0];
  const float* W_ih0  = (const float*)d_in[4];
  const float* W_hh0  = (const float*)d_in[5];
  const float* b_ih0  = (const float*)d_in[6];
  const float* b_hh0  = (const float*)d_in[7];
  const float* W_ih1  = (const float*)d_in[8];
  const float* W_hh1  = (const float*)d_in[9];
  const float* b_ih1  = (const float*)d_in[10];
  const float* b_hh1  = (const float*)d_in[11];
  const float* W_proj = (const float*)d_in[12];
  const float* b_proj = (const float*)d_in[13];
  float* outp = (float*)d_out;

  hipLaunchKernelGGL(zero_bar_kernel, dim3(1), dim3(64), 0, stream);
  hipMemsetAsync(d_out, 0, (size_t)out_size * sizeof(float), stream);

  hipFuncSetAttribute((const void*)gru2_fused,
                      hipFuncAttributeMaxDynamicSharedMemorySize, (int)LDS_BYTES);

  const float* a0 = x_enc;
  const float* a1 = W_ih0;  const float* a2 = W_hh0;
  const float* a3 = b_ih0;  const float* a4 = b_hh0;
  const float* a5 = W_ih1;  const float* a6 = W_hh1;
  const float* a7 = b_ih1;  const float* a8 = b_hh1;
  const float* a9 = W_proj; const float* a10 = b_proj;
  float* a11 = outp;
  void* args[] = { &a0,&a1,&a2,&a3,&a4,&a5,&a6,&a7,&a8,&a9,&a10,&a11 };

  hipError_t e = hipLaunchCooperativeKernel((const void*)gru2_fused,
                                            dim3(NBLK), dim3(NTHR), args,
                                            (unsigned)LDS_BYTES, stream);
  if (e != hipSuccess) {
    hipLaunchKernelGGL(gru2_fused, dim3(NBLK), dim3(NTHR), LDS_BYTES, stream,
                       x_enc, W_ih0, W_hh0, b_ih0, b_hh0,
                       W_ih1, W_hh1, b_ih1, b_hh1, W_proj, b_proj, outp);
  }
}

// Round 7
// 20290.445 us; speedup vs baseline: 1.1035x; 1.1035x over previous
//
#include <hip/hip_runtime.h>
#include <cmath>

// ============================================================================
// Fused 2-layer GRU (B=128, T=512, d=512) + projection, fp32.
// ONE persistent cooperative kernel, 256 WGs x 512 thr (8 waves = 2/SIMD).
// Pipeline skew: iter g computes L0 step g AND L1 step g-1.
// r7 change (r6 evidence: dur invariant to 2x waves; ~35us/iter fixed stall):
//   DECONTENDED BARRIER. Old: 4 groups' counters in ONE 64B line; 256 RMWs +
//   continuous polls serialize at one L3 slice (~tens of us/iter). New:
//   per-group ARRIVAL line (RMW-only, nobody reads) + separate FLAG line
//   (read-only polls, s_sleep(8)); last arriver publishes the epoch.
//   Everything else byte-identical to r6.
// ============================================================================

#define TSEQ   512
#define NB     128
#define DM     512
#define ENCF   21
#define PREDL  96
#define TSTART 416
#define NTHR   512
#define NBLK   256

// LDS layout (float indices) — unchanged (155,936 B)
#define L_WHH0 0                    // [24][512] swizzled
#define L_WHH1 (24*DM)              // [24][512] swizzled
#define L_HCH  (2*24*DM)            // [32][128] swizzled h chunk
#define L_SC0  (L_HCH + 32*128)     // [4][32][33] reduce scratch L0
#define L_SC1  (L_SC0 + 4*32*33)    // [4][32][33] reduce scratch L1
#define L_BIA0 (L_SC1 + 4*32*33)    // 48
#define L_BIA1 (L_BIA0 + 48)        // 48
#define L_WIH0 (L_BIA1 + 48)        // [24][24]
#define L_XCH  (L_WIH0 + 24*24)     // [32][24]
#define L_WP   (L_XCH + 32*24)      // [21][8]
#define L_HNT  (L_WP + 168)         // [32][8]
#define LDS_FLOATS (L_HNT + 256)
#define LDS_BYTES  (LDS_FLOATS * 4)

// uniform bank-quad swizzle: bits {2,4} from row bits {0,1}
#define SWZB(x) (((((x) & 1) << 2)) | ((((x) & 2)) << 3))

__device__ float g_h0A[NB * DM];
__device__ float g_h0B[NB * DM];
__device__ float g_h1A[NB * DM];
__device__ float g_h1B[NB * DM];
// barrier state: 4 groups x 64-uint (256 B) spread -> distinct cache lines
__device__ unsigned g_arr[4 * 64];    // arrival counters (RMW only, never read)
__device__ unsigned g_flag[4 * 64];   // epoch flags (read-only polls + 1 store)

extern "C" __global__ void zero_bar_kernel() {
  int t = threadIdx.x;
  if (t < 4 * 64) {
    __hip_atomic_store(&g_arr[t],  0u, __ATOMIC_RELAXED, __HIP_MEMORY_SCOPE_AGENT);
    __hip_atomic_store(&g_flag[t], 0u, __ATOMIC_RELAXED, __HIP_MEMORY_SCOPE_AGENT);
  }
}

__device__ __forceinline__ float sigf(float x) { return 1.0f / (1.0f + expf(-x)); }

// device-coherent relaxed atomic accesses (coherence point = L3)
__device__ __forceinline__ float2 ld2_dc(const float* p) {
  unsigned long long v = __hip_atomic_load((unsigned long long*)p,
                                           __ATOMIC_RELAXED, __HIP_MEMORY_SCOPE_AGENT);
  union { unsigned long long u; float2 f; } cv; cv.u = v; return cv.f;
}
__device__ __forceinline__ float ld_dc(const float* p) {
  unsigned v = __hip_atomic_load((unsigned*)p,
                                 __ATOMIC_RELAXED, __HIP_MEMORY_SCOPE_AGENT);
  union { unsigned u; float f; } cv; cv.u = v; return cv.f;
}
__device__ __forceinline__ void st_dc(float* p, float v) {
  union { float f; unsigned u; } cv; cv.f = v;
  __hip_atomic_store((unsigned*)p, cv.u, __ATOMIC_RELAXED, __HIP_MEMORY_SCOPE_AGENT);
}

extern "C" __global__ __launch_bounds__(NTHR)
void gru2_fused(const float* __restrict__ x_enc,
                const float* __restrict__ Wih0, const float* __restrict__ Whh0,
                const float* __restrict__ bih0, const float* __restrict__ bhh0,
                const float* __restrict__ Wih1, const float* __restrict__ Whh1,
                const float* __restrict__ bih1, const float* __restrict__ bhh1,
                const float* __restrict__ Wproj, const float* __restrict__ bproj,
                float* __restrict__ outp)
{
  extern __shared__ float lds[];

  const int tid  = threadIdx.x;
  const int bid  = blockIdx.x;
  const int bt   = bid & 3;         // batch group (32 rows), barrier group
  const int jt   = bid >> 2;        // j tile 0..63 (8 hidden units)
  const int b0   = bt << 5;
  const int j0   = jt << 3;
  const int l    = tid & 63;
  const int wv   = tid >> 6;        // wave 0..7
  const int wq   = wv & 3;          // k-wave within half (scratch slot)
  const int half = wv >> 2;         // batch half: rows 0-15 / 16-31
  const int pr   = l & 3;           // row position
  const int pb4  = (l >> 2) & 3;    // batch position mod 4
  const int kg   = l >> 4;          // lane k-group 0..3

  const float2 z2 = make_float2(0.f, 0.f);

  // ---- one-time staging: W_hh0/W_hh1 (swizzled), W_ih0, biases, W_proj ----
  for (int f = tid; f < 24 * 128; f += NTHR) {
    int r = f >> 7, w4 = f & 127;
    int R = ((r >> 3) << 9) + j0 + (r & 7);
    int dst = r * DM + ((w4 << 2) ^ SWZB(r));
    *(float4*)(lds + L_WHH0 + dst) = *(const float4*)(Whh0 + (size_t)R * DM + (w4 << 2));
    *(float4*)(lds + L_WHH1 + dst) = *(const float4*)(Whh1 + (size_t)R * DM + (w4 << 2));
  }
  for (int idx = tid; idx < 24 * ENCF; idx += NTHR) {
    int r = idx / ENCF, kx = idx - r * ENCF;
    int R = ((r >> 3) << 9) + j0 + (r & 7);
    lds[L_WIH0 + r * 24 + kx] = Wih0[R * ENCF + kx];
  }
  if (tid < 24) {
    int R = ((tid >> 3) << 9) + j0 + (tid & 7);
    lds[L_BIA0 + tid]      = bhh0[R];
    lds[L_BIA0 + 24 + tid] = bih0[R];
    lds[L_BIA1 + tid]      = bhh1[R];
    lds[L_BIA1 + 24 + tid] = bih1[R];
  }
  for (int idx = tid; idx < 21 * 8; idx += NTHR) {
    int o = idx >> 3, j = idx & 7;
    lds[L_WP + idx] = Wproj[o * DM + j0 + j];
  }
  // visibility covered by first __syncthreads in the chunk loop

#pragma unroll 1
  for (int g = 0; g <= TSEQ; ++g) {
    const float* h0r = (g & 1) ? g_h0A : g_h0B;   // h0_{g-1}
    float*       h0w = (g & 1) ? g_h0B : g_h0A;   // h0_g
    const float* h1r = (g & 1) ? g_h1B : g_h1A;   // h1_{g-2}
    float*       h1w = (g & 1) ? g_h1A : g_h1B;   // h1_{g-1}

    // ---- iteration-top prefetches (hide L3 latency under pass A) ----
    const int gx = (g < TSEQ) ? g : (TSEQ - 1);
    float rx[2];
#pragma unroll
    for (int q = 0; q < 2; ++q) {
      int idx = tid + (q << 9);
      float v = 0.0f;
      if (idx < 32 * ENCF) {
        int row = idx / ENCF, kx = idx - row * ENCF;
        v = x_enc[((size_t)(b0 + row) * TSEQ + gx) * ENCF + kx];
      }
      rx[q] = v;
    }
    float h0prev = 0.f, h1prev = 0.f;
    size_t hix = 0;
    if (tid < 256) {
      int b = tid >> 3, j = tid & 7;
      hix = (size_t)(b0 + b) * DM + j0 + j;
      if (g > 0) h0prev = ld_dc(h0r + hix);
      if (g > 1) h1prev = ld_dc(h1r + hix);
    }
    float2 ph0[4], ph1[4];
#pragma unroll
    for (int q = 0; q < 4; ++q) {
      int idx = tid + (q << 9);            // 0..2047 doubles
      int row = idx >> 6, c2 = idx & 63;
      size_t off = (size_t)(b0 + row) * DM + (c2 << 1);
      ph0[q] = (g == 0) ? z2 : ld2_dc(h0r + off);
      ph1[q] = (g <= 1) ? z2 : ld2_dc(h1r + off);
    }

    float accA[4][6], accX[4][6];
#pragma unroll
    for (int i = 0; i < 4; ++i)
#pragma unroll
      for (int m = 0; m < 6; ++m) { accA[i][m] = 0.0f; accX[i][m] = 0.0f; }

    // ---- pass A+B: h0_{g-1} x (W_hh0 from LDS, W_ih1 from global/L2) ----
#pragma unroll 1
    for (int c = 0; c < 4; ++c) {
      __syncthreads();                             // prev chunk compute done
#pragma unroll
      for (int q = 0; q < 4; ++q) {
        int idx = tid + (q << 9);
        int row = idx >> 6, cf = (idx & 63) << 1;
        *(float2*)(lds + L_HCH + row * 128 + (cf ^ SWZB(row))) = ph0[q];
      }
      __syncthreads();
      if (c < 3) {
#pragma unroll
        for (int q = 0; q < 4; ++q) {
          int idx = tid + (q << 9);
          int row = idx >> 6, c2 = idx & 63;
          ph0[q] = (g == 0) ? z2
                 : ld2_dc(h0r + (size_t)(b0 + row) * DM + ((c + 1) << 7) + (c2 << 1));
        }
      }
      float4 wx[6][2];
#pragma unroll
      for (int m = 0; m < 6; ++m) {
        int r = pr + (m << 2);
        int R = ((r >> 3) << 9) + j0 + (r & 7);
#pragma unroll
        for (int q = 0; q < 2; ++q) {
          int ww = (wq << 3) + (kg << 1) + q;
          wx[m][q] = *(const float4*)(Wih1 + (size_t)R * DM + (((c << 5) + ww) << 2));
        }
      }
#pragma unroll
      for (int q = 0; q < 2; ++q) {
        int ww = (wq << 3) + (kg << 1) + q;
        int colf = ((c << 5) + ww) << 2;
        float4 wh[6];
#pragma unroll
        for (int m = 0; m < 6; ++m) {
          int r = pr + (m << 2);
          wh[m] = *(const float4*)(lds + L_WHH0 + r * DM + (colf ^ SWZB(r)));
        }
#pragma unroll
        for (int i = 0; i < 4; ++i) {
          int b = pb4 + (i << 2) + (half << 4);
          float4 hv = *(const float4*)(lds + L_HCH + b * 128 + ((ww << 2) ^ SWZB(b)));
#pragma unroll
          for (int m = 0; m < 6; ++m) {
            accA[i][m] += hv.x * wh[m].x + hv.y * wh[m].y + hv.z * wh[m].z + hv.w * wh[m].w;
            accX[i][m] += hv.x * wx[m][q].x + hv.y * wx[m][q].y + hv.z * wx[m][q].z + hv.w * wx[m][q].w;
          }
        }
      }
    }

    // reduce A -> sc0 (=), X -> sc1 (=); lane kg-groups via shfl
#pragma unroll
    for (int i = 0; i < 4; ++i)
#pragma unroll
      for (int m = 0; m < 6; ++m) {
        float a = accA[i][m]; a += __shfl_xor(a, 16); a += __shfl_xor(a, 32); accA[i][m] = a;
        float x = accX[i][m]; x += __shfl_xor(x, 16); x += __shfl_xor(x, 32); accX[i][m] = x;
      }
    if (kg == 0) {
#pragma unroll
      for (int i = 0; i < 4; ++i) {
        int b = pb4 + (i << 2) + (half << 4);
        float* s0 = lds + L_SC0 + (wq * 32 + b) * 33;
        float* s1 = lds + L_SC1 + (wq * 32 + b) * 33;
#pragma unroll
        for (int m = 0; m < 6; ++m) {
          int r = pr + (m << 2);
          s0[r] = accA[i][m];
          s1[(m < 4) ? r : (r + 8)] = accX[i][m];   // n-gate x-part at 24..31
        }
      }
    }

    // ---- pass C: h1_{g-2} x W_hh1 (LDS); chunk0 already in ph1 ----
#pragma unroll
    for (int i = 0; i < 4; ++i)
#pragma unroll
      for (int m = 0; m < 6; ++m) accA[i][m] = 0.0f;

#pragma unroll 1
    for (int c = 0; c < 4; ++c) {
      __syncthreads();
#pragma unroll
      for (int q = 0; q < 4; ++q) {
        int idx = tid + (q << 9);
        int row = idx >> 6, cf = (idx & 63) << 1;
        *(float2*)(lds + L_HCH + row * 128 + (cf ^ SWZB(row))) = ph1[q];
      }
      __syncthreads();
      if (c < 3) {
#pragma unroll
        for (int q = 0; q < 4; ++q) {
          int idx = tid + (q << 9);
          int row = idx >> 6, c2 = idx & 63;
          ph1[q] = (g <= 1) ? z2
                 : ld2_dc(h1r + (size_t)(b0 + row) * DM + ((c + 1) << 7) + (c2 << 1));
        }
      }
#pragma unroll
      for (int q = 0; q < 2; ++q) {
        int ww = (wq << 3) + (kg << 1) + q;
        int colf = ((c << 5) + ww) << 2;
        float4 wh[6];
#pragma unroll
        for (int m = 0; m < 6; ++m) {
          int r = pr + (m << 2);
          wh[m] = *(const float4*)(lds + L_WHH1 + r * DM + (colf ^ SWZB(r)));
        }
#pragma unroll
        for (int i = 0; i < 4; ++i) {
          int b = pb4 + (i << 2) + (half << 4);
          float4 hv = *(const float4*)(lds + L_HCH + b * 128 + ((ww << 2) ^ SWZB(b)));
#pragma unroll
          for (int m = 0; m < 6; ++m)
            accA[i][m] += hv.x * wh[m].x + hv.y * wh[m].y + hv.z * wh[m].z + hv.w * wh[m].w;
        }
      }
    }

    // reduce C -> sc1: rows 0..15 (+=, join x-part), 16..23 (=, n-gate h-part)
#pragma unroll
    for (int i = 0; i < 4; ++i)
#pragma unroll
      for (int m = 0; m < 6; ++m) {
        float a = accA[i][m]; a += __shfl_xor(a, 16); a += __shfl_xor(a, 32); accA[i][m] = a;
      }
    if (kg == 0) {
#pragma unroll
      for (int i = 0; i < 4; ++i) {
        int b = pb4 + (i << 2) + (half << 4);
        float* s1 = lds + L_SC1 + (wq * 32 + b) * 33;
#pragma unroll
        for (int m = 0; m < 6; ++m) {
          int r = pr + (m << 2);
          if (m < 4) s1[r] += accA[i][m];          // same thread wrote '=' above
          else       s1[r]  = accA[i][m];
        }
      }
    }

    // stage x slice for L0 gate threads
#pragma unroll
    for (int q = 0; q < 2; ++q) {
      int idx = tid + (q << 9);
      if (idx < 32 * ENCF) {
        int row = idx / ENCF, kx = idx - row * ENCF;
        lds[L_XCH + row * 24 + kx] = rx[q];
      }
    }
    __syncthreads();

    // ---- gates: threads 0..255 -> (b = tid>>3, j = tid&7) ----
    if (tid < 256) {
      int b = tid >> 3, j = tid & 7;
      float sR0 = 0.f, sZ0 = 0.f, sN0 = 0.f;
      float sR1 = 0.f, sZ1 = 0.f, sN1h = 0.f, sN1x = 0.f;
#pragma unroll
      for (int w = 0; w < 4; ++w) {
        const float* s0 = lds + L_SC0 + (w * 32 + b) * 33;
        const float* s1 = lds + L_SC1 + (w * 32 + b) * 33;
        sR0 += s0[j]; sZ0 += s0[8 + j]; sN0 += s0[16 + j];
        sR1 += s1[j]; sZ1 += s1[8 + j]; sN1h += s1[16 + j]; sN1x += s1[24 + j];
      }
      if (g < TSEQ) {
        float xr = 0.f, xz = 0.f, xn = 0.f;
        const float* xrow = lds + L_XCH + b * 24;
#pragma unroll
        for (int k = 0; k < ENCF; ++k) {
          float xv = xrow[k];
          xr += xv * lds[L_WIH0 + j * 24 + k];
          xz += xv * lds[L_WIH0 + (8 + j) * 24 + k];
          xn += xv * lds[L_WIH0 + (16 + j) * 24 + k];
        }
        float r0 = sigf(xr + lds[L_BIA0 + 24 + j] + sR0 + lds[L_BIA0 + j]);
        float z0 = sigf(xz + lds[L_BIA0 + 32 + j] + sZ0 + lds[L_BIA0 + 8 + j]);
        float n0 = tanhf(xn + lds[L_BIA0 + 40 + j] + r0 * (sN0 + lds[L_BIA0 + 16 + j]));
        st_dc(h0w + hix, (1.0f - z0) * n0 + z0 * h0prev);
      }
      if (g >= 1) {
        float r1 = sigf(sR1 + lds[L_BIA1 + 24 + j] + lds[L_BIA1 + j]);
        float z1 = sigf(sZ1 + lds[L_BIA1 + 32 + j] + lds[L_BIA1 + 8 + j]);
        float n1 = tanhf(sN1x + lds[L_BIA1 + 40 + j] + r1 * (sN1h + lds[L_BIA1 + 16 + j]));
        float h1n = (1.0f - z1) * n1 + z1 * h1prev;
        st_dc(h1w + hix, h1n);
        lds[L_HNT + (b << 3) + j] = h1n;
      }
    }

    // ---- fused projection: h1_{g-1}, steps 416..511 -> iters 417..512 ----
    if (g >= TSTART + 1) {
      __syncthreads();
      int tp = g - 1 - TSTART;
#pragma unroll
      for (int q = 0; q < 2; ++q) {
        int idx = tid + (q << 9);
        if (idx < 32 * ENCF) {
          int b = idx / ENCF, o = idx - b * ENCF;
          const float* hb = lds + L_HNT + (b << 3);
          const float* wo = lds + L_WP + (o << 3);
          float v = hb[0] * wo[0] + hb[1] * wo[1] + hb[2] * wo[2] + hb[3] * wo[3]
                  + hb[4] * wo[4] + hb[5] * wo[5] + hb[6] * wo[6] + hb[7] * wo[7];
          if (jt == 0) v += bproj[o];
          atomicAdd(outp + ((size_t)(b0 + b) * PREDL + tp) * ENCF + o, v);
        }
      }
    }

    // ---- inter-WG barrier (64 WGs per batch group), decontended ----
    // arrival line: RMW-only (nobody loads it). flag line: read-only polls +
    // one store by the last arriver. 4 groups on 4 separate line pairs.
    __syncthreads();                 // all h stores issued by this WG
    if (tid == 0) {
      asm volatile("s_waitcnt vmcnt(0) lgkmcnt(0)" ::: "memory");  // h stores at L3
      unsigned tgt = 64u * (unsigned)(g + 1);
      unsigned old = __hip_atomic_fetch_add(&g_arr[bt << 6], 1u,
                                            __ATOMIC_RELAXED, __HIP_MEMORY_SCOPE_AGENT);
      if (old == tgt - 1u) {
        // last arriver of this epoch: all 64 adds (and thus all h stores) done
        __hip_atomic_store(&g_flag[bt << 6], tgt,
                           __ATOMIC_RELAXED, __HIP_MEMORY_SCOPE_AGENT);
      } else {
        while (__hip_atomic_load(&g_flag[bt << 6],
                                 __ATOMIC_RELAXED, __HIP_MEMORY_SCOPE_AGENT) < tgt)
          __builtin_amdgcn_s_sleep(8);
      }
    }
    __syncthreads();
    asm volatile("" ::: "memory");
  }
}

extern "C" void kernel_launch(void* const* d_in, const int* in_sizes, int n_in,
                              void* d_out, int out_size, void* d_ws, size_t ws_size,
                              hipStream_t stream)
{
  (void)in_sizes; (void)n_in; (void)d_ws; (void)ws_size;
  const float* x_enc  = (const float*)d_in[0];
  const float* W_ih0  = (const float*)d_in[4];
  const float* W_hh0  = (const float*)d_in[5];
  const float* b_ih0  = (const float*)d_in[6];
  const float* b_hh0  = (const float*)d_in[7];
  const float* W_ih1  = (const float*)d_in[8];
  const float* W_hh1  = (const float*)d_in[9];
  const float* b_ih1  = (const float*)d_in[10];
  const float* b_hh1  = (const float*)d_in[11];
  const float* W_proj = (const float*)d_in[12];
  const float* b_proj = (const float*)d_in[13];
  float* outp = (float*)d_out;

  hipLaunchKernelGGL(zero_bar_kernel, dim3(1), dim3(256), 0, stream);
  hipMemsetAsync(d_out, 0, (size_t)out_size * sizeof(float), stream);

  hipFuncSetAttribute((const void*)gru2_fused,
                      hipFuncAttributeMaxDynamicSharedMemorySize, (int)LDS_BYTES);

  const float* a0 = x_enc;
  const float* a1 = W_ih0;  const float* a2 = W_hh0;
  const float* a3 = b_ih0;  const float* a4 = b_hh0;
  const float* a5 = W_ih1;  const float* a6 = W_hh1;
  const float* a7 = b_ih1;  const float* a8 = b_hh1;
  const float* a9 = W_proj; const float* a10 = b_proj;
  float* a11 = outp;
  void* args[] = { &a0,&a1,&a2,&a3,&a4,&a5,&a6,&a7,&a8,&a9,&a10,&a11 };

  hipError_t e = hipLaunchCooperativeKernel((const void*)gru2_fused,
                                            dim3(NBLK), dim3(NTHR), args,
                                            (unsigned)LDS_BYTES, stream);
  if (e != hipSuccess) {
    hipLaunchKernelGGL(gru2_fused, dim3(NBLK), dim3(NTHR), LDS_BYTES, stream,
                       x_enc, W_ih0, W_hh0, b_ih0, b_hh0,
                       W_ih1, W_hh1, b_ih1, b_hh1, W_proj, b_proj, outp);
  }
}